// Round 1
// baseline (8249.598 us; speedup 1.0000x reference)
//
#include <hip/hip_runtime.h>
#include <hip/hip_bf16.h>

// ---------------------------------------------------------------------------
// MambaEncoder forward, fp32 correctness-first baseline.
// SEQ=4096, D_MODEL=1024, D_INNER=2048, D_STATE=16, DT_RANK=64, N_LAYERS=4
// ---------------------------------------------------------------------------

#define SEQ     4096
#define DMODEL  1024
#define DINNER  2048
#define NSTATE  16
#define DTRANK  64
#define NLAYERS 4
#define LC      64   // scan chunk length
#define NC      64   // number of chunks (SEQ/LC)
#define DG      16   // channels per scan block

// ---------------------------------------------------------------- block sum
__device__ __forceinline__ float block_sum(float v, float* red, int nwaves) {
    #pragma unroll
    for (int o = 32; o > 0; o >>= 1) v += __shfl_down(v, o, 64);
    int lane = threadIdx.x & 63, w = threadIdx.x >> 6;
    __syncthreads();                 // protect red[] from previous use
    if (lane == 0) red[w] = v;
    __syncthreads();
    float s = red[0];
    for (int i = 1; i < nwaves; i++) s += red[i];
    return s;
}

// ------------------------------------------------------------- layernorm row
// out[s,:] = LN(X[s,:] (+ X2[s,:])) * g + b
template<int WIDTH>
__global__ void ln_kernel(const float* __restrict__ X, const float* __restrict__ X2,
                          const float* __restrict__ g, const float* __restrict__ bta,
                          float* __restrict__ out, float eps) {
    constexpr int E = WIDTH / 256;
    __shared__ float red[4];
    int s = blockIdx.x, tid = threadIdx.x;
    size_t base = (size_t)s * WIDTH;
    float v[E]; float sum = 0.f;
    #pragma unroll
    for (int i = 0; i < E; i++) {
        int c = tid + i * 256;
        float t = X[base + c];
        if (X2) t += X2[base + c];
        v[i] = t; sum += t;
    }
    float mu = block_sum(sum, red, 4) * (1.f / WIDTH);
    float sq = 0.f;
    #pragma unroll
    for (int i = 0; i < E; i++) { float d = v[i] - mu; sq += d * d; }
    float var = block_sum(sq, red, 4) * (1.f / WIDTH);
    float rstd = rsqrtf(var + eps);
    #pragma unroll
    for (int i = 0; i < E; i++) {
        int c = tid + i * 256;
        out[base + c] = (v[i] - mu) * rstd * g[c] + bta[c];
    }
}

// --------------------------------------------------- outnorm + silu(z) gate
// y[s,:] = LN(y[s,:])*g+b  * silu(xz[s, 2048+c]);  in-place on y
__global__ void outnorm_silu_kernel(float* __restrict__ y, const float* __restrict__ xz,
                                    const float* __restrict__ g, const float* __restrict__ bta,
                                    float eps) {
    constexpr int WIDTH = DINNER, E = WIDTH / 256;
    __shared__ float red[4];
    int s = blockIdx.x, tid = threadIdx.x;
    size_t base = (size_t)s * WIDTH;
    float v[E]; float sum = 0.f;
    #pragma unroll
    for (int i = 0; i < E; i++) { int c = tid + i * 256; v[i] = y[base + c]; sum += v[i]; }
    float mu = block_sum(sum, red, 4) * (1.f / WIDTH);
    float sq = 0.f;
    #pragma unroll
    for (int i = 0; i < E; i++) { float d = v[i] - mu; sq += d * d; }
    float var = block_sum(sq, red, 4) * (1.f / WIDTH);
    float rstd = rsqrtf(var + eps);
    #pragma unroll
    for (int i = 0; i < E; i++) {
        int c = tid + i * 256;
        float ln = (v[i] - mu) * rstd * g[c] + bta[c];
        float z = xz[(size_t)s * (2 * DINNER) + DINNER + c];
        float sig = 1.f / (1.f + expf(-z));
        y[base + c] = ln * (z * sig);
    }
}

// ------------------------------------------------------- depthwise conv, k=3
__global__ void conv_kernel(const float* __restrict__ xz, const float* __restrict__ cw,
                            const float* __restrict__ cb, float* __restrict__ u) {
    int gid = blockIdx.x * 256 + threadIdx.x;   // SEQ*DINNER
    int s = gid >> 11, c = gid & (DINNER - 1);
    size_t row = (size_t)s * (2 * DINNER);
    float x0 = xz[row + c];
    float xm = (s > 0)       ? xz[row - 2 * DINNER + c] : 0.f;
    float xp = (s < SEQ - 1) ? xz[row + 2 * DINNER + c] : 0.f;
    u[gid] = cw[c * 3 + 0] * xm + cw[c * 3 + 1] * x0 + cw[c * 3 + 2] * xp + cb[c];
}

// ------------------------------------------------------------------- SGEMM
// C[M,N] = act( A[M,K](lda) @ W[N,K](ldw)^T + bias ) + res
// ACT: 0=none, 1=softplus
template<int ACT, bool HAS_BIAS, bool HAS_RES>
__global__ void sgemm_kernel(const float* __restrict__ A, int lda,
                             const float* __restrict__ W, int ldw,
                             const float* __restrict__ bias,
                             const float* __restrict__ res, int ldres,
                             float* __restrict__ C, int ldc,
                             int M, int N, int K) {
    constexpr int BM = 64, BN = 64, BK = 16, TM = 4, TN = 4;
    __shared__ float As[BK][BM];
    __shared__ float Ws[BK][BN];
    int tid = threadIdx.x;
    int tm = tid >> 4, tn = tid & 15;
    int m0 = blockIdx.x * BM, n0 = blockIdx.y * BN;
    float acc[TM][TN] = {};
    for (int k0 = 0; k0 < K; k0 += BK) {
        #pragma unroll
        for (int i = 0; i < 4; i++) {
            int idx = tid * 4 + i;               // 0..1023
            int mm = idx >> 4, kk = idx & 15;
            int gm = m0 + mm, gk = k0 + kk;
            As[kk][mm] = (gm < M && gk < K) ? A[(size_t)gm * lda + gk] : 0.f;
            int gn = n0 + mm;
            Ws[kk][mm] = (gn < N && gk < K) ? W[(size_t)gn * ldw + gk] : 0.f;
        }
        __syncthreads();
        #pragma unroll
        for (int kk = 0; kk < BK; kk++) {
            float a[TM], w[TN];
            #pragma unroll
            for (int i = 0; i < TM; i++) a[i] = As[kk][tm * TM + i];
            #pragma unroll
            for (int j = 0; j < TN; j++) w[j] = Ws[kk][tn * TN + j];
            #pragma unroll
            for (int i = 0; i < TM; i++)
                #pragma unroll
                for (int j = 0; j < TN; j++) acc[i][j] += a[i] * w[j];
        }
        __syncthreads();
    }
    #pragma unroll
    for (int i = 0; i < TM; i++) {
        int row = m0 + tm * TM + i; if (row >= M) continue;
        #pragma unroll
        for (int j = 0; j < TN; j++) {
            int col = n0 + tn * TN + j; if (col >= N) continue;
            float v = acc[i][j];
            if (HAS_BIAS) v += bias[col];
            if (ACT == 1) v = (v > 20.f) ? v : log1pf(expf(v));
            if (HAS_RES) v += res[(size_t)row * ldres + col];
            C[(size_t)row * ldc + col] = v;
        }
    }
}

// ------------------------------------------------------- chunked scan pass 1
// per (chunk k, channel-group dg): local scan from h=0; emit h_end, dsum
__global__ void scan1_kernel(const float* __restrict__ delta, const float* __restrict__ u,
                             const float* __restrict__ dbc, const float* __restrict__ A_log,
                             float* __restrict__ h_end, float* __restrict__ dsum) {
    __shared__ float sD[LC][DG], sU[LC][DG], sB[LC][NSTATE];
    int k = blockIdx.x, dg = blockIdx.y;
    int d0 = dg * DG, s0 = k * LC, tid = threadIdx.x;
    #pragma unroll
    for (int i = 0; i < 4; i++) {
        int idx = tid + i * 256;                 // 1024 elements
        int r = idx >> 4, c = idx & 15;
        sD[r][c] = delta[(size_t)(s0 + r) * DINNER + d0 + c];
        sU[r][c] = u[(size_t)(s0 + r) * DINNER + d0 + c];
        sB[r][c] = dbc[(size_t)(s0 + r) * 96 + DTRANK + c];
    }
    __syncthreads();
    int c = tid >> 4, n = tid & 15;
    int d = d0 + c;
    float a = -expf(A_log[d * NSTATE + n]);
    float h = 0.f, ds = 0.f;
    for (int r = 0; r < LC; r++) {
        float dl = sD[r][c];
        h = expf(dl * a) * h + dl * sU[r][c] * sB[r][n];
        ds += dl;
    }
    h_end[((size_t)k * DINNER + d) * NSTATE + n] = h;
    if (n == 0) dsum[k * DINNER + d] = ds;
}

// ------------------------------------------------------- chunked scan pass 2
// inter-chunk recurrence; emits per-chunk initial states
__global__ void scan2_kernel(const float* __restrict__ A_log, const float* __restrict__ dsum,
                             const float* __restrict__ h_end, float* __restrict__ hinit) {
    int id = blockIdx.x * 256 + threadIdx.x;     // DINNER*NSTATE = 32768
    int d = id >> 4;
    float a = -expf(A_log[id]);
    float h = 0.f;
    for (int k = 0; k < NC; k++) {
        hinit[(size_t)k * (DINNER * NSTATE) + id] = h;
        h = expf(a * dsum[k * DINNER + d]) * h + h_end[(size_t)k * (DINNER * NSTATE) + id];
    }
}

// ------------------------------------------------------- chunked scan pass 3
// re-scan chunk with correct h_init, emit y (in-place over delta buffer)
__global__ void scan3_kernel(float* __restrict__ delta_y, const float* __restrict__ u,
                             const float* __restrict__ dbc, const float* __restrict__ A_log,
                             const float* __restrict__ Dp, const float* __restrict__ hinit) {
    __shared__ float sD[LC][DG], sU[LC][DG], sB[LC][NSTATE], sC[LC][NSTATE];
    int k = blockIdx.x, dg = blockIdx.y;
    int d0 = dg * DG, s0 = k * LC, tid = threadIdx.x;
    #pragma unroll
    for (int i = 0; i < 4; i++) {
        int idx = tid + i * 256;
        int r = idx >> 4, c = idx & 15;
        sD[r][c] = delta_y[(size_t)(s0 + r) * DINNER + d0 + c];
        sU[r][c] = u[(size_t)(s0 + r) * DINNER + d0 + c];
        sB[r][c] = dbc[(size_t)(s0 + r) * 96 + DTRANK + c];
        sC[r][c] = dbc[(size_t)(s0 + r) * 96 + DTRANK + NSTATE + c];
    }
    __syncthreads();
    int c = tid >> 4, n = tid & 15;
    int d = d0 + c;
    float a = -expf(A_log[d * NSTATE + n]);
    float dpv = Dp[d];
    float h = hinit[(size_t)k * (DINNER * NSTATE) + d * NSTATE + n];
    for (int r = 0; r < LC; r++) {
        float dl = sD[r][c];
        float uu = sU[r][c];
        h = expf(dl * a) * h + dl * uu * sB[r][n];
        float p = h * sC[r][n];
        p += __shfl_xor(p, 1, 64);
        p += __shfl_xor(p, 2, 64);
        p += __shfl_xor(p, 4, 64);
        p += __shfl_xor(p, 8, 64);
        if (n == 0) delta_y[(size_t)(s0 + r) * DINNER + d] = p + uu * dpv;
    }
}

// ---------------------------------------------------------------------------
extern "C" void kernel_launch(void* const* d_in, const int* in_sizes, int n_in,
                              void* d_out, int out_size, void* d_ws, size_t ws_size,
                              hipStream_t stream) {
    const float* x         = (const float*)d_in[0];
    const float* pos       = (const float*)d_in[1];
    const float* ln_g      = (const float*)d_in[2];
    const float* ln_b      = (const float*)d_in[3];
    const float* innorm_g  = (const float*)d_in[4];
    const float* innorm_b  = (const float*)d_in[5];
    const float* in_proj_w = (const float*)d_in[6];
    const float* in_proj_b = (const float*)d_in[7];
    const float* conv_w    = (const float*)d_in[8];
    const float* conv_b    = (const float*)d_in[9];
    const float* deltaBC_w = (const float*)d_in[10];
    const float* dt_proj_w = (const float*)d_in[11];
    const float* dt_proj_b = (const float*)d_in[12];
    const float* A_log     = (const float*)d_in[13];
    const float* Dp        = (const float*)d_in[14];
    const float* outnorm_g = (const float*)d_in[15];
    const float* outnorm_b = (const float*)d_in[16];
    const float* out_proj_w= (const float*)d_in[17];
    const float* out_proj_b= (const float*)d_in[18];

    float* enc = (float*)d_out;                  // residual stream lives in d_out
    char* ws = (char*)d_ws;
    const size_t MB = 1024 * 1024;
    float* h     = (float*)(ws + 0 * MB);        // 16 MB  [S, d]
    float* xz    = (float*)(ws + 16 * MB);       // 64 MB  [S, 2*di]
    float* u     = (float*)(ws + 80 * MB);       // 32 MB  [S, di]
    float* dlt   = (float*)(ws + 112 * MB);      // 32 MB  delta -> y -> p (in place)
    float* dbc   = (float*)(ws + 144 * MB);      // 2  MB  [S, 96]
    float* h_end = (float*)(ws + 146 * MB);      // 8  MB  [NC, di, n]
    float* dsum  = (float*)(ws + 154 * MB);      // 1  MB  [NC, di]
    float* hinit = (float*)(ws + 155 * MB);      // 8  MB  [NC, di, n]

    // enc = LN(x + pos_enc), eps=1e-6
    ln_kernel<DMODEL><<<SEQ, 256, 0, stream>>>(x, pos, ln_g, ln_b, enc, 1e-6f);

    for (int L = 0; L < NLAYERS; L++) {
        const float* Al = A_log + (size_t)L * DINNER * NSTATE;
        // h = LN(enc), eps=1e-5
        ln_kernel<DMODEL><<<SEQ, 256, 0, stream>>>(enc, nullptr, innorm_g + L * DMODEL,
                                                   innorm_b + L * DMODEL, h, 1e-5f);
        // xz = h @ in_proj_w^T + b        [4096 x 4096], K=1024
        sgemm_kernel<0, true, false><<<dim3(64, 64), 256, 0, stream>>>(
            h, DMODEL, in_proj_w + (size_t)L * 2 * DINNER * DMODEL, DMODEL,
            in_proj_b + (size_t)L * 2 * DINNER, nullptr, 0,
            xz, 2 * DINNER, SEQ, 2 * DINNER, DMODEL);
        // u = depthwise conv3(x1) + cb
        conv_kernel<<<(SEQ * DINNER) / 256, 256, 0, stream>>>(
            xz, conv_w + (size_t)L * DINNER * 3, conv_b + L * DINNER, u);
        // dbc = u @ deltaBC_w^T           [4096 x 96], K=2048
        sgemm_kernel<0, false, false><<<dim3(64, 2), 256, 0, stream>>>(
            u, DINNER, deltaBC_w + (size_t)L * 96 * DINNER, DINNER,
            nullptr, nullptr, 0, dbc, 96, SEQ, 96, DINNER);
        // delta = softplus(dbc[:, :64] @ dt_proj_w^T + dt_b)   [4096 x 2048], K=64
        sgemm_kernel<1, true, false><<<dim3(64, 32), 256, 0, stream>>>(
            dbc, 96, dt_proj_w + (size_t)L * DINNER * DTRANK, DTRANK,
            dt_proj_b + L * DINNER, nullptr, 0, dlt, DINNER, SEQ, DINNER, DTRANK);
        // selective scan (3-pass chunked), y overwrites delta buffer
        scan1_kernel<<<dim3(NC, DINNER / DG), 256, 0, stream>>>(dlt, u, dbc, Al, h_end, dsum);
        scan2_kernel<<<(DINNER * NSTATE) / 256, 256, 0, stream>>>(Al, dsum, h_end, hinit);
        scan3_kernel<<<dim3(NC, DINNER / DG), 256, 0, stream>>>(dlt, u, dbc, Al,
                                                                Dp + L * DINNER, hinit);
        // p = LN(y)*g+b * silu(z1)  (in place on dlt)
        outnorm_silu_kernel<<<SEQ, 256, 0, stream>>>(dlt, xz, outnorm_g + L * DINNER,
                                                     outnorm_b + L * DINNER, 1e-5f);
        // enc = p @ out_proj_w^T + b + enc   [4096 x 1024], K=2048
        sgemm_kernel<0, true, true><<<dim3(64, 16), 256, 0, stream>>>(
            dlt, DINNER, out_proj_w + (size_t)L * DMODEL * DINNER, DINNER,
            out_proj_b + L * DMODEL, enc, DMODEL, enc, DMODEL, SEQ, DMODEL, DINNER);
    }
}

// Round 2
// 1763.498 us; speedup vs baseline: 4.6780x; 4.6780x over previous
//
#include <hip/hip_runtime.h>
#include <hip/hip_bf16.h>
#include <stdint.h>

// ---------------------------------------------------------------------------
// MambaEncoder forward. Round 1: bf16 MFMA GEMMs (m97 structure) for all four
// projections; fp32 everywhere else. SEQ=4096, D=1024, DI=2048, N=16, R=64, L=4
// ---------------------------------------------------------------------------

#define SEQ     4096
#define DMODEL  1024
#define DINNER  2048
#define NSTATE  16
#define DTRANK  64
#define NLAYERS 4
#define LC      64   // scan chunk length
#define NC      64   // number of chunks (SEQ/LC)
#define DG      16   // channels per scan block

typedef __attribute__((ext_vector_type(8))) short short8v;   // 8 bf16 (4 VGPRs)
typedef __attribute__((ext_vector_type(4))) float f32x4;

// ------------------------------------------------------------ async g->LDS 16B
__device__ __forceinline__ void gld16(const void* gsrc, void* ldst) {
    __builtin_amdgcn_global_load_lds(
        (const __attribute__((address_space(1))) void*)gsrc,
        (__attribute__((address_space(3))) void*)ldst, 16, 0, 0);
}

// ---------------------------------------------------------------- block sum
__device__ __forceinline__ float block_sum(float v, float* red, int nwaves) {
    #pragma unroll
    for (int o = 32; o > 0; o >>= 1) v += __shfl_down(v, o, 64);
    int lane = threadIdx.x & 63, w = threadIdx.x >> 6;
    __syncthreads();
    if (lane == 0) red[w] = v;
    __syncthreads();
    float s = red[0];
    for (int i = 1; i < nwaves; i++) s += red[i];
    return s;
}

// ------------------------------------------------------------- layernorm row
template<int WIDTH, typename OutT>
__global__ void ln_kernel(const float* __restrict__ X, const float* __restrict__ X2,
                          const float* __restrict__ g, const float* __restrict__ bta,
                          OutT* __restrict__ out, float eps) {
    constexpr int E = WIDTH / 256;
    __shared__ float red[4];
    int s = blockIdx.x, tid = threadIdx.x;
    size_t base = (size_t)s * WIDTH;
    float v[E]; float sum = 0.f;
    #pragma unroll
    for (int i = 0; i < E; i++) {
        int c = tid + i * 256;
        float t = X[base + c];
        if (X2) t += X2[base + c];
        v[i] = t; sum += t;
    }
    float mu = block_sum(sum, red, 4) * (1.f / WIDTH);
    float sq = 0.f;
    #pragma unroll
    for (int i = 0; i < E; i++) { float d = v[i] - mu; sq += d * d; }
    float var = block_sum(sq, red, 4) * (1.f / WIDTH);
    float rstd = rsqrtf(var + eps);
    #pragma unroll
    for (int i = 0; i < E; i++) {
        int c = tid + i * 256;
        float r = (v[i] - mu) * rstd * g[c] + bta[c];
        out[base + c] = (OutT)r;
    }
}

// --------------------------------------------------- outnorm + silu(z) gate
// p_bf[s,:] = bf16( (LN(y[s,:])*g+b) * silu(xz[s, 2048+c]) )
__global__ void outnorm_silu_kernel(const float* __restrict__ y, const float* __restrict__ xz,
                                    const float* __restrict__ g, const float* __restrict__ bta,
                                    __hip_bfloat16* __restrict__ p_bf, float eps) {
    constexpr int WIDTH = DINNER, E = WIDTH / 256;
    __shared__ float red[4];
    int s = blockIdx.x, tid = threadIdx.x;
    size_t base = (size_t)s * WIDTH;
    float v[E]; float sum = 0.f;
    #pragma unroll
    for (int i = 0; i < E; i++) { int c = tid + i * 256; v[i] = y[base + c]; sum += v[i]; }
    float mu = block_sum(sum, red, 4) * (1.f / WIDTH);
    float sq = 0.f;
    #pragma unroll
    for (int i = 0; i < E; i++) { float d = v[i] - mu; sq += d * d; }
    float var = block_sum(sq, red, 4) * (1.f / WIDTH);
    float rstd = rsqrtf(var + eps);
    #pragma unroll
    for (int i = 0; i < E; i++) {
        int c = tid + i * 256;
        float ln = (v[i] - mu) * rstd * g[c] + bta[c];
        float z = xz[(size_t)s * (2 * DINNER) + DINNER + c];
        float sig = 1.f / (1.f + expf(-z));
        p_bf[base + c] = __float2bfloat16(ln * (z * sig));
    }
}

// ------------------------------------------------------- depthwise conv, k=3
__global__ void conv_kernel(const float* __restrict__ xz, const float* __restrict__ cw,
                            const float* __restrict__ cb, __hip_bfloat16* __restrict__ u_bf) {
    int gid = blockIdx.x * 256 + threadIdx.x;   // SEQ*DINNER
    int s = gid >> 11, c = gid & (DINNER - 1);
    size_t row = (size_t)s * (2 * DINNER);
    float x0 = xz[row + c];
    float xm = (s > 0)       ? xz[row - 2 * DINNER + c] : 0.f;
    float xp = (s < SEQ - 1) ? xz[row + 2 * DINNER + c] : 0.f;
    float u = cw[c * 3 + 0] * xm + cw[c * 3 + 1] * x0 + cw[c * 3 + 2] * xp + cb[c];
    u_bf[gid] = __float2bfloat16(u);
}

// ---------------------------------------------------------- fp32 -> bf16 cvt
__global__ void cvt_bf16_kernel(const float* __restrict__ in,
                                __hip_bfloat16* __restrict__ out) {
    int i = (blockIdx.x * 256 + threadIdx.x) * 4;
    float4 v = *(const float4*)(in + i);
    __hip_bfloat162 t0, t1;
    t0.x = __float2bfloat16(v.x); t0.y = __float2bfloat16(v.y);
    t1.x = __float2bfloat16(v.z); t1.y = __float2bfloat16(v.w);
    __hip_bfloat162* o = (__hip_bfloat162*)(out + i);
    o[0] = t0; o[1] = t1;
}

// --------------------------------------------------------- bf16 MFMA GEMM
// C[M,N] = epi( A[M,K](lda) @ W[N,K](ldw)^T )
// MODE 0: +bias (in_proj)        MODE 1: dbc (no bias, N=96 bound, dual write)
// MODE 2: +bias, softplus (dt)   MODE 3: +bias, +res (out_proj)
// BM=BN=128, BK=32; 256 thr = 4 waves in 2x2, each wave 64x64 (4x4 mfma tiles)
template<int MODE>
__global__ __launch_bounds__(256, 2)
void mfma_gemm(const __hip_bfloat16* __restrict__ A, int lda,
               const __hip_bfloat16* __restrict__ W, int ldw,
               const float* __restrict__ bias,
               float* __restrict__ C, int ldc,
               const float* __restrict__ res,
               __hip_bfloat16* __restrict__ Cbf,
               int M, int N, int K) {
    __shared__ __attribute__((aligned(16))) short sA[128][32];
    __shared__ __attribute__((aligned(16))) short sB[128][32];
    int tid = threadIdx.x;
    int lane = tid & 63, w = tid >> 6;
    int wm = w >> 1, wn = w & 1;
    int m0 = blockIdx.x * 128, n0 = blockIdx.y * 128;
    int r16 = lane & 15, quad = lane >> 4;
    int ldrow = (lane >> 2);          // 0..15 within wave's staging stripe
    int c8 = (lane & 3) * 8;          // k element offset for 16B load

    f32x4 acc[4][4] = {};

    for (int k0 = 0; k0 < K; k0 += 32) {
        __syncthreads();
        // stage A: rows j*64 + w*16 + ldrow, 16B each
        #pragma unroll
        for (int j = 0; j < 2; j++) {
            int row = j * 64 + w * 16 + ldrow;
            gld16(A + (size_t)(m0 + row) * lda + k0 + c8,
                  (char*)&sA[0][0] + j * 4096 + w * 1024);
            int nr = n0 + row; if (nr > N - 1) nr = N - 1;   // clamp (MODE 1)
            gld16(W + (size_t)nr * ldw + k0 + c8,
                  (char*)&sB[0][0] + j * 4096 + w * 1024);
        }
        __syncthreads();
        short8v aF[4], bF[4];
        #pragma unroll
        for (int mi = 0; mi < 4; mi++)
            aF[mi] = *(const short8v*)&sA[wm * 64 + mi * 16 + r16][quad * 8];
        #pragma unroll
        for (int ni = 0; ni < 4; ni++)
            bF[ni] = *(const short8v*)&sB[wn * 64 + ni * 16 + r16][quad * 8];
        #pragma unroll
        for (int mi = 0; mi < 4; mi++)
            #pragma unroll
            for (int ni = 0; ni < 4; ni++)
                acc[mi][ni] = __builtin_amdgcn_mfma_f32_16x16x32_bf16(
                    aF[mi], bF[ni], acc[mi][ni], 0, 0, 0);
    }

    // epilogue: D col = lane&15, row = quad*4 + r
    #pragma unroll
    for (int mi = 0; mi < 4; mi++) {
        #pragma unroll
        for (int ni = 0; ni < 4; ni++) {
            f32x4 a = acc[mi][ni];
            int col = n0 + wn * 64 + ni * 16 + r16;
            int rbase = m0 + wm * 64 + mi * 16 + quad * 4;
            #pragma unroll
            for (int r = 0; r < 4; r++) {
                int row = rbase + r;
                float v = a[r];
                if (MODE == 0 || MODE == 2 || MODE == 3) v += bias[col];
                if (MODE == 2) v = (v > 20.f) ? v : log1pf(expf(v));
                if (MODE == 3) v += res[(size_t)row * ldc + col];
                if (MODE == 1) {
                    if (col < 96) {
                        C[(size_t)row * 96 + col] = v;
                        if (col < 64) Cbf[(size_t)row * 64 + col] = __float2bfloat16(v);
                    }
                } else {
                    C[(size_t)row * ldc + col] = v;
                }
            }
        }
    }
}

// ------------------------------------------------------- chunked scan pass 1
__global__ void scan1_kernel(const float* __restrict__ delta, const __hip_bfloat16* __restrict__ u,
                             const float* __restrict__ dbc, const float* __restrict__ A_log,
                             float* __restrict__ h_end, float* __restrict__ dsum) {
    __shared__ float sD[LC][DG], sU[LC][DG], sB[LC][NSTATE];
    int k = blockIdx.x, dg = blockIdx.y;
    int d0 = dg * DG, s0 = k * LC, tid = threadIdx.x;
    #pragma unroll
    for (int i = 0; i < 4; i++) {
        int idx = tid + i * 256;                 // 1024 elements
        int r = idx >> 4, c = idx & 15;
        sD[r][c] = delta[(size_t)(s0 + r) * DINNER + d0 + c];
        sU[r][c] = __bfloat162float(u[(size_t)(s0 + r) * DINNER + d0 + c]);
        sB[r][c] = dbc[(size_t)(s0 + r) * 96 + DTRANK + c];
    }
    __syncthreads();
    int c = tid >> 4, n = tid & 15;
    int d = d0 + c;
    float a = -expf(A_log[d * NSTATE + n]);
    float h = 0.f, ds = 0.f;
    for (int r = 0; r < LC; r++) {
        float dl = sD[r][c];
        h = expf(dl * a) * h + dl * sU[r][c] * sB[r][n];
        ds += dl;
    }
    h_end[((size_t)k * DINNER + d) * NSTATE + n] = h;
    if (n == 0) dsum[k * DINNER + d] = ds;
}

// ------------------------------------------------------- chunked scan pass 2
__global__ void scan2_kernel(const float* __restrict__ A_log, const float* __restrict__ dsum,
                             const float* __restrict__ h_end, float* __restrict__ hinit) {
    int id = blockIdx.x * 256 + threadIdx.x;     // DINNER*NSTATE = 32768
    int d = id >> 4;
    float a = -expf(A_log[id]);
    float h = 0.f;
    for (int k = 0; k < NC; k++) {
        hinit[(size_t)k * (DINNER * NSTATE) + id] = h;
        h = expf(a * dsum[k * DINNER + d]) * h + h_end[(size_t)k * (DINNER * NSTATE) + id];
    }
}

// ------------------------------------------------------- chunked scan pass 3
__global__ void scan3_kernel(float* __restrict__ delta_y, const __hip_bfloat16* __restrict__ u,
                             const float* __restrict__ dbc, const float* __restrict__ A_log,
                             const float* __restrict__ Dp, const float* __restrict__ hinit) {
    __shared__ float sD[LC][DG], sU[LC][DG], sB[LC][NSTATE], sC[LC][NSTATE];
    int k = blockIdx.x, dg = blockIdx.y;
    int d0 = dg * DG, s0 = k * LC, tid = threadIdx.x;
    #pragma unroll
    for (int i = 0; i < 4; i++) {
        int idx = tid + i * 256;
        int r = idx >> 4, c = idx & 15;
        sD[r][c] = delta_y[(size_t)(s0 + r) * DINNER + d0 + c];
        sU[r][c] = __bfloat162float(u[(size_t)(s0 + r) * DINNER + d0 + c]);
        sB[r][c] = dbc[(size_t)(s0 + r) * 96 + DTRANK + c];
        sC[r][c] = dbc[(size_t)(s0 + r) * 96 + DTRANK + NSTATE + c];
    }
    __syncthreads();
    int c = tid >> 4, n = tid & 15;
    int d = d0 + c;
    float a = -expf(A_log[d * NSTATE + n]);
    float dpv = Dp[d];
    float h = hinit[(size_t)k * (DINNER * NSTATE) + d * NSTATE + n];
    for (int r = 0; r < LC; r++) {
        float dl = sD[r][c];
        float uu = sU[r][c];
        h = expf(dl * a) * h + dl * uu * sB[r][n];
        float p = h * sC[r][n];
        p += __shfl_xor(p, 1, 64);
        p += __shfl_xor(p, 2, 64);
        p += __shfl_xor(p, 4, 64);
        p += __shfl_xor(p, 8, 64);
        if (n == 0) delta_y[(size_t)(s0 + r) * DINNER + d] = p + uu * dpv;
    }
}

// ---------------------------------------------------------------------------
extern "C" void kernel_launch(void* const* d_in, const int* in_sizes, int n_in,
                              void* d_out, int out_size, void* d_ws, size_t ws_size,
                              hipStream_t stream) {
    const float* x         = (const float*)d_in[0];
    const float* pos       = (const float*)d_in[1];
    const float* ln_g      = (const float*)d_in[2];
    const float* ln_b      = (const float*)d_in[3];
    const float* innorm_g  = (const float*)d_in[4];
    const float* innorm_b  = (const float*)d_in[5];
    const float* in_proj_w = (const float*)d_in[6];
    const float* in_proj_b = (const float*)d_in[7];
    const float* conv_w    = (const float*)d_in[8];
    const float* conv_b    = (const float*)d_in[9];
    const float* deltaBC_w = (const float*)d_in[10];
    const float* dt_proj_w = (const float*)d_in[11];
    const float* dt_proj_b = (const float*)d_in[12];
    const float* A_log     = (const float*)d_in[13];
    const float* Dp        = (const float*)d_in[14];
    const float* outnorm_g = (const float*)d_in[15];
    const float* outnorm_b = (const float*)d_in[16];
    const float* out_proj_w= (const float*)d_in[17];
    const float* out_proj_b= (const float*)d_in[18];

    typedef __hip_bfloat16 bf16;
    float* enc = (float*)d_out;                  // residual stream lives in d_out
    char* ws = (char*)d_ws;
    const size_t MB = 1024 * 1024;
    bf16*  h_bf   = (bf16*) (ws + 0);            //  8 MB [S, d]       (aliased w/ p_bf)
    bf16*  p_bf   = (bf16*) (ws + 0);            // 16 MB [S, di]      (after in_proj done)
    float* xz     = (float*)(ws + 16 * MB);      // 64 MB [S, 2*di]
    float* dlt    = (float*)(ws + 80 * MB);      // 32 MB delta -> y (in place)
    bf16*  u_bf   = (bf16*) (ws + 112 * MB);     // 16 MB [S, di]
    float* dbc    = (float*)(ws + 128 * MB);     // 1.5MB [S, 96]
    bf16*  dbc_bf = (bf16*) (ws + 130 * MB);     // 0.5MB [S, 64]
    float* h_end  = (float*)(ws + 131 * MB);     //  8 MB [NC, di, n]
    float* hinit  = (float*)(ws + 139 * MB);     //  8 MB [NC, di, n]
    float* dsum   = (float*)(ws + 147 * MB);     // 0.5MB [NC, di]
    bf16*  w_in   = (bf16*) (ws + 148 * MB);     //  8 MB [2di, d]
    bf16*  w_dbc  = (bf16*) (ws + 156 * MB);     // .38MB [96, di]
    bf16*  w_dt   = (bf16*) (ws + 157 * MB);     // .25MB [di, r]
    bf16*  w_out  = (bf16*) (ws + 158 * MB);     //  4 MB [d, di]

    // enc = LN(x + pos_enc), eps=1e-6, fp32 out
    ln_kernel<DMODEL, float><<<SEQ, 256, 0, stream>>>(x, pos, ln_g, ln_b, enc, 1e-6f);

    for (int L = 0; L < NLAYERS; L++) {
        const float* Al = A_log + (size_t)L * DINNER * NSTATE;
        // per-layer weight conversions fp32 -> bf16
        cvt_bf16_kernel<<<(2 * DINNER * DMODEL) / 1024, 256, 0, stream>>>(
            in_proj_w + (size_t)L * 2 * DINNER * DMODEL, w_in);
        cvt_bf16_kernel<<<(96 * DINNER) / 1024, 256, 0, stream>>>(
            deltaBC_w + (size_t)L * 96 * DINNER, w_dbc);
        cvt_bf16_kernel<<<(DINNER * DTRANK) / 1024, 256, 0, stream>>>(
            dt_proj_w + (size_t)L * DINNER * DTRANK, w_dt);
        cvt_bf16_kernel<<<(DMODEL * DINNER) / 1024, 256, 0, stream>>>(
            out_proj_w + (size_t)L * DMODEL * DINNER, w_out);

        // h_bf = bf16(LN(enc)), eps=1e-5
        ln_kernel<DMODEL, bf16><<<SEQ, 256, 0, stream>>>(enc, nullptr, innorm_g + L * DMODEL,
                                                         innorm_b + L * DMODEL, h_bf, 1e-5f);
        // xz = h @ in_proj_w^T + b   [4096 x 4096], K=1024
        mfma_gemm<0><<<dim3(32, 32), 256, 0, stream>>>(
            h_bf, DMODEL, w_in, DMODEL, in_proj_b + (size_t)L * 2 * DINNER,
            xz, 2 * DINNER, nullptr, nullptr, SEQ, 2 * DINNER, DMODEL);
        // u_bf = depthwise conv3(x1) + cb
        conv_kernel<<<(SEQ * DINNER) / 256, 256, 0, stream>>>(
            xz, conv_w + (size_t)L * DINNER * 3, conv_b + L * DINNER, u_bf);
        // dbc = u @ deltaBC_w^T   [4096 x 96], K=2048 (fp32 out + bf16 delta cols)
        mfma_gemm<1><<<dim3(32, 1), 256, 0, stream>>>(
            u_bf, DINNER, w_dbc, DINNER, nullptr,
            dbc, 96, nullptr, dbc_bf, SEQ, 96, DINNER);
        // delta = softplus(dbc[:, :64] @ dt_proj_w^T + dt_b)  [4096 x 2048], K=64
        mfma_gemm<2><<<dim3(32, 16), 256, 0, stream>>>(
            dbc_bf, DTRANK, w_dt, DTRANK, dt_proj_b + L * DINNER,
            dlt, DINNER, nullptr, nullptr, SEQ, DINNER, DTRANK);
        // selective scan (3-pass chunked), y overwrites delta buffer
        scan1_kernel<<<dim3(NC, DINNER / DG), 256, 0, stream>>>(dlt, u_bf, dbc, Al, h_end, dsum);
        scan2_kernel<<<(DINNER * NSTATE) / 256, 256, 0, stream>>>(Al, dsum, h_end, hinit);
        scan3_kernel<<<dim3(NC, DINNER / DG), 256, 0, stream>>>(dlt, u_bf, dbc, Al,
                                                                Dp + L * DINNER, hinit);
        // p_bf = bf16( (LN(y)*g+b) * silu(z1) )
        outnorm_silu_kernel<<<SEQ, 256, 0, stream>>>(dlt, xz, outnorm_g + L * DINNER,
                                                     outnorm_b + L * DINNER, p_bf, 1e-5f);
        // enc = p @ out_proj_w^T + b + enc   [4096 x 1024], K=2048
        mfma_gemm<3><<<dim3(32, 8), 256, 0, stream>>>(
            p_bf, DINNER, w_out, DINNER, out_proj_b + L * DMODEL,
            enc, DMODEL, enc, nullptr, SEQ, DMODEL, DINNER);
    }
}

// Round 3
// 1219.518 us; speedup vs baseline: 6.7646x; 1.4461x over previous
//
#include <hip/hip_runtime.h>
#include <hip/hip_bf16.h>
#include <stdint.h>

// ---------------------------------------------------------------------------
// MambaEncoder forward. Round 2: register-resident selective scan (16 states
// per thread, no shuffles), split-K dbc GEMM, bf16 xz stream.
// ---------------------------------------------------------------------------

#define SEQ     4096
#define DMODEL  1024
#define DINNER  2048
#define NSTATE  16
#define DTRANK  64
#define NLAYERS 4
#define LC      32    // scan chunk length
#define NC      128   // number of chunks (SEQ/LC)

typedef __attribute__((ext_vector_type(8))) short short8v;   // 8 bf16 (4 VGPRs)
typedef __attribute__((ext_vector_type(4))) float f32x4;
typedef __hip_bfloat16 bf16;

__device__ __forceinline__ float b2f(unsigned short x) {
    unsigned int u = ((unsigned int)x) << 16;
    return __builtin_bit_cast(float, u);
}

// ------------------------------------------------------------ async g->LDS 16B
__device__ __forceinline__ void gld16(const void* gsrc, void* ldst) {
    __builtin_amdgcn_global_load_lds(
        (const __attribute__((address_space(1))) void*)gsrc,
        (__attribute__((address_space(3))) void*)ldst, 16, 0, 0);
}

// ---------------------------------------------------------------- block sum
__device__ __forceinline__ float block_sum(float v, float* red, int nwaves) {
    #pragma unroll
    for (int o = 32; o > 0; o >>= 1) v += __shfl_down(v, o, 64);
    int lane = threadIdx.x & 63, w = threadIdx.x >> 6;
    __syncthreads();
    if (lane == 0) red[w] = v;
    __syncthreads();
    float s = red[0];
    for (int i = 1; i < nwaves; i++) s += red[i];
    return s;
}

// ------------------------------------------------------------- layernorm row
template<int WIDTH, typename OutT>
__global__ void ln_kernel(const float* __restrict__ X, const float* __restrict__ X2,
                          const float* __restrict__ g, const float* __restrict__ bta,
                          OutT* __restrict__ out, float eps) {
    constexpr int E = WIDTH / 256;
    __shared__ float red[4];
    int s = blockIdx.x, tid = threadIdx.x;
    size_t base = (size_t)s * WIDTH;
    float v[E]; float sum = 0.f;
    #pragma unroll
    for (int i = 0; i < E; i++) {
        int c = tid + i * 256;
        float t = X[base + c];
        if (X2) t += X2[base + c];
        v[i] = t; sum += t;
    }
    float mu = block_sum(sum, red, 4) * (1.f / WIDTH);
    float sq = 0.f;
    #pragma unroll
    for (int i = 0; i < E; i++) { float d = v[i] - mu; sq += d * d; }
    float var = block_sum(sq, red, 4) * (1.f / WIDTH);
    float rstd = rsqrtf(var + eps);
    #pragma unroll
    for (int i = 0; i < E; i++) {
        int c = tid + i * 256;
        float r = (v[i] - mu) * rstd * g[c] + bta[c];
        out[base + c] = (OutT)r;
    }
}

// --------------------------------------------------- outnorm + silu(z) gate
__global__ void outnorm_silu_kernel(const float* __restrict__ y, const bf16* __restrict__ xz,
                                    const float* __restrict__ g, const float* __restrict__ bta,
                                    bf16* __restrict__ p_bf, float eps) {
    constexpr int WIDTH = DINNER, E = WIDTH / 256;
    __shared__ float red[4];
    int s = blockIdx.x, tid = threadIdx.x;
    size_t base = (size_t)s * WIDTH;
    const unsigned short* xzu = (const unsigned short*)xz;
    float v[E]; float sum = 0.f;
    #pragma unroll
    for (int i = 0; i < E; i++) { int c = tid + i * 256; v[i] = y[base + c]; sum += v[i]; }
    float mu = block_sum(sum, red, 4) * (1.f / WIDTH);
    float sq = 0.f;
    #pragma unroll
    for (int i = 0; i < E; i++) { float d = v[i] - mu; sq += d * d; }
    float var = block_sum(sq, red, 4) * (1.f / WIDTH);
    float rstd = rsqrtf(var + eps);
    #pragma unroll
    for (int i = 0; i < E; i++) {
        int c = tid + i * 256;
        float ln = (v[i] - mu) * rstd * g[c] + bta[c];
        float z = b2f(xzu[(size_t)s * (2 * DINNER) + DINNER + c]);
        float sig = 1.f / (1.f + __expf(-z));
        p_bf[base + c] = __float2bfloat16(ln * (z * sig));
    }
}

// ------------------------------------------------------- depthwise conv, k=3
// 4 channels per thread, bf16 in/out
__global__ void conv_kernel(const bf16* __restrict__ xz, const float* __restrict__ cw,
                            const float* __restrict__ cb, bf16* __restrict__ u_bf) {
    int t = blockIdx.x * 256 + threadIdx.x;     // SEQ * 512
    int s = t >> 9, c = (t & 511) * 4;
    size_t row = (size_t)s * (2 * DINNER);
    const unsigned short* xp = (const unsigned short*)xz;
    ushort4 z4 = {0, 0, 0, 0};
    ushort4 v0 = *(const ushort4*)(xp + row + c);
    ushort4 vm = (s > 0)       ? *(const ushort4*)(xp + row - 2 * DINNER + c) : z4;
    ushort4 vp = (s < SEQ - 1) ? *(const ushort4*)(xp + row + 2 * DINNER + c) : z4;
    unsigned short o[4];
    float x0[4] = {b2f(v0.x), b2f(v0.y), b2f(v0.z), b2f(v0.w)};
    float xm[4] = {b2f(vm.x), b2f(vm.y), b2f(vm.z), b2f(vm.w)};
    float xp4[4] = {b2f(vp.x), b2f(vp.y), b2f(vp.z), b2f(vp.w)};
    #pragma unroll
    for (int i = 0; i < 4; i++) {
        int ch = c + i;
        float u = cw[ch * 3 + 0] * xm[i] + cw[ch * 3 + 1] * x0[i]
                + cw[ch * 3 + 2] * xp4[i] + cb[ch];
        o[i] = __builtin_bit_cast(unsigned short, __float2bfloat16(u));
    }
    *(ushort4*)((unsigned short*)u_bf + (size_t)s * DINNER + c) = {o[0], o[1], o[2], o[3]};
}

// ---------------------------------------------------------- fp32 -> bf16 cvt
__global__ void cvt_bf16_kernel(const float* __restrict__ in, bf16* __restrict__ out) {
    int i = (blockIdx.x * 256 + threadIdx.x) * 4;
    float4 v = *(const float4*)(in + i);
    __hip_bfloat162 t0, t1;
    t0.x = __float2bfloat16(v.x); t0.y = __float2bfloat16(v.y);
    t1.x = __float2bfloat16(v.z); t1.y = __float2bfloat16(v.w);
    __hip_bfloat162* o = (__hip_bfloat162*)(out + i);
    o[0] = t0; o[1] = t1;
}

// --------------------------------------------------------- bf16 MFMA GEMM
// MODE 0: +bias, bf16 out (in_proj)   MODE 1: split-K partial, N=96 (dbc)
// MODE 2: +bias, softplus, f32 out    MODE 3: +bias, +res, f32 out (out_proj)
template<int MODE>
__global__ __launch_bounds__(256, 2)
void mfma_gemm(const bf16* __restrict__ A, int lda,
               const bf16* __restrict__ W, int ldw,
               const float* __restrict__ bias,
               float* __restrict__ C, int ldc,
               const float* __restrict__ res,
               bf16* __restrict__ Cbf,
               int M, int N, int K) {
    __shared__ __attribute__((aligned(16))) short sA[128][32];
    __shared__ __attribute__((aligned(16))) short sB[128][32];
    int tid = threadIdx.x;
    int lane = tid & 63, w = tid >> 6;
    int wm = w >> 1, wn = w & 1;
    int m0 = blockIdx.x * 128, n0 = blockIdx.y * 128;
    int r16 = lane & 15, quad = lane >> 4;
    int ldrow = (lane >> 2);
    int c8 = (lane & 3) * 8;

    if (MODE == 1) {       // split-K: this block covers K-range [kz*K, (kz+1)*K)
        int kz = blockIdx.z;
        A += (size_t)kz * K;
        W += (size_t)kz * K;
        C += (size_t)kz * M * 96;
    }

    f32x4 acc[4][4] = {};

    for (int k0 = 0; k0 < K; k0 += 32) {
        __syncthreads();
        #pragma unroll
        for (int j = 0; j < 2; j++) {
            int row = j * 64 + w * 16 + ldrow;
            gld16(A + (size_t)(m0 + row) * lda + k0 + c8,
                  (char*)&sA[0][0] + j * 4096 + w * 1024);
            int nr = n0 + row; if (nr > N - 1) nr = N - 1;   // clamp (MODE 1)
            gld16(W + (size_t)nr * ldw + k0 + c8,
                  (char*)&sB[0][0] + j * 4096 + w * 1024);
        }
        __syncthreads();
        short8v aF[4], bF[4];
        #pragma unroll
        for (int mi = 0; mi < 4; mi++)
            aF[mi] = *(const short8v*)&sA[wm * 64 + mi * 16 + r16][quad * 8];
        #pragma unroll
        for (int ni = 0; ni < 4; ni++)
            bF[ni] = *(const short8v*)&sB[wn * 64 + ni * 16 + r16][quad * 8];
        #pragma unroll
        for (int mi = 0; mi < 4; mi++)
            #pragma unroll
            for (int ni = 0; ni < 4; ni++)
                acc[mi][ni] = __builtin_amdgcn_mfma_f32_16x16x32_bf16(
                    aF[mi], bF[ni], acc[mi][ni], 0, 0, 0);
    }

    #pragma unroll
    for (int mi = 0; mi < 4; mi++) {
        #pragma unroll
        for (int ni = 0; ni < 4; ni++) {
            f32x4 a = acc[mi][ni];
            int col = n0 + wn * 64 + ni * 16 + r16;
            int rbase = m0 + wm * 64 + mi * 16 + quad * 4;
            #pragma unroll
            for (int r = 0; r < 4; r++) {
                int row = rbase + r;
                float v = a[r];
                if (MODE == 0 || MODE == 2 || MODE == 3) v += bias[col];
                if (MODE == 2) v = (v > 20.f) ? v : log1pf(__expf(v));
                if (MODE == 3) v += res[(size_t)row * ldc + col];
                if (MODE == 1) {
                    if (col < 96) C[(size_t)row * 96 + col] = v;
                } else if (MODE == 0) {
                    Cbf[(size_t)row * ldc + col] = __float2bfloat16(v);
                } else {
                    C[(size_t)row * ldc + col] = v;
                }
            }
        }
    }
}

// -------------------------------------------- reduce split-K partials of dbc
__global__ void reduce_dbc_kernel(const float* __restrict__ p, float* __restrict__ dbc,
                                  bf16* __restrict__ dbc_bf) {
    int i = blockIdx.x * 256 + threadIdx.x;      // SEQ*96
    const int SP = SEQ * 96;
    float v = p[i] + p[i + SP] + p[i + 2 * SP] + p[i + 3 * SP];
    dbc[i] = v;
    int row = i / 96, c = i - row * 96;
    if (c < DTRANK) dbc_bf[(size_t)row * DTRANK + c] = __float2bfloat16(v);
}

// ------------------------------------------------------- chunked scan pass 1
// thread = (chunk k, channel d); 16 states in registers
__global__ void scan1_kernel(const float* __restrict__ delta, const bf16* __restrict__ u,
                             const float* __restrict__ dbc, const float* __restrict__ A_log,
                             float* __restrict__ h_end, float* __restrict__ dsum) {
    __shared__ __attribute__((aligned(16))) float sB[LC][NSTATE];
    int k = blockIdx.x, d = blockIdx.y * 256 + threadIdx.x;
    int s0 = k * LC, tid = threadIdx.x;
    #pragma unroll
    for (int i = 0; i < 2; i++) {
        int idx = tid + i * 256;                 // LC*16 = 512
        int r = idx >> 4, n = idx & 15;
        sB[r][n] = dbc[(size_t)(s0 + r) * 96 + DTRANK + n];
    }
    float a[NSTATE];
    #pragma unroll
    for (int n = 0; n < NSTATE; n++) a[n] = -__expf(A_log[(size_t)d * NSTATE + n]);
    __syncthreads();
    const unsigned short* uu16 = (const unsigned short*)u;
    float h[NSTATE] = {}; float ds = 0.f;
    #pragma unroll 2
    for (int r = 0; r < LC; r++) {
        float dl = delta[(size_t)(s0 + r) * DINNER + d];
        float du = dl * b2f(uu16[(size_t)(s0 + r) * DINNER + d]);
        ds += dl;
        float Bv[NSTATE];
        #pragma unroll
        for (int q = 0; q < 4; q++) *(float4*)&Bv[q * 4] = *(const float4*)&sB[r][q * 4];
        #pragma unroll
        for (int n = 0; n < NSTATE; n++)
            h[n] = __expf(dl * a[n]) * h[n] + du * Bv[n];
    }
    #pragma unroll
    for (int n = 0; n < NSTATE; n++)
        h_end[((size_t)k * NSTATE + n) * DINNER + d] = h[n];
    dsum[(size_t)k * DINNER + d] = ds;
}

// ------------------------------------------------------- chunked scan pass 2
__global__ void scan2_kernel(const float* __restrict__ A_log, const float* __restrict__ dsum,
                             const float* __restrict__ h_end, float* __restrict__ hinit) {
    int id = blockIdx.x * 256 + threadIdx.x;     // DINNER*NSTATE
    int d = id & (DINNER - 1), n = id >> 11;
    float a = -__expf(A_log[(size_t)d * NSTATE + n]);
    float h = 0.f;
    for (int k = 0; k < NC; k++) {
        size_t off = ((size_t)k * NSTATE + n) * DINNER + d;
        hinit[off] = h;
        h = __expf(a * dsum[(size_t)k * DINNER + d]) * h + h_end[off];
    }
}

// ------------------------------------------------------- chunked scan pass 3
__global__ void scan3_kernel(float* __restrict__ delta_y, const bf16* __restrict__ u,
                             const float* __restrict__ dbc, const float* __restrict__ A_log,
                             const float* __restrict__ Dp, const float* __restrict__ hinit) {
    __shared__ __attribute__((aligned(16))) float sB[LC][NSTATE];
    __shared__ __attribute__((aligned(16))) float sC[LC][NSTATE];
    int k = blockIdx.x, d = blockIdx.y * 256 + threadIdx.x;
    int s0 = k * LC, tid = threadIdx.x;
    #pragma unroll
    for (int i = 0; i < 4; i++) {
        int idx = tid + i * 256;                 // LC*32 = 1024
        int r = idx >> 5, c = idx & 31;
        float v = dbc[(size_t)(s0 + r) * 96 + DTRANK + c];
        if (c < 16) sB[r][c] = v; else sC[r][c - 16] = v;
    }
    float a[NSTATE];
    #pragma unroll
    for (int n = 0; n < NSTATE; n++) a[n] = -__expf(A_log[(size_t)d * NSTATE + n]);
    float h[NSTATE];
    #pragma unroll
    for (int n = 0; n < NSTATE; n++)
        h[n] = hinit[((size_t)k * NSTATE + n) * DINNER + d];
    float dpv = Dp[d];
    __syncthreads();
    const unsigned short* uu16 = (const unsigned short*)u;
    #pragma unroll 2
    for (int r = 0; r < LC; r++) {
        float dl = delta_y[(size_t)(s0 + r) * DINNER + d];
        float uu = b2f(uu16[(size_t)(s0 + r) * DINNER + d]);
        float du = dl * uu;
        float Bv[NSTATE], Cv[NSTATE];
        #pragma unroll
        for (int q = 0; q < 4; q++) {
            *(float4*)&Bv[q * 4] = *(const float4*)&sB[r][q * 4];
            *(float4*)&Cv[q * 4] = *(const float4*)&sC[r][q * 4];
        }
        float y = uu * dpv;
        #pragma unroll
        for (int n = 0; n < NSTATE; n++) {
            h[n] = __expf(dl * a[n]) * h[n] + du * Bv[n];
            y += h[n] * Cv[n];
        }
        delta_y[(size_t)(s0 + r) * DINNER + d] = y;
    }
}

// ---------------------------------------------------------------------------
extern "C" void kernel_launch(void* const* d_in, const int* in_sizes, int n_in,
                              void* d_out, int out_size, void* d_ws, size_t ws_size,
                              hipStream_t stream) {
    const float* x         = (const float*)d_in[0];
    const float* pos       = (const float*)d_in[1];
    const float* ln_g      = (const float*)d_in[2];
    const float* ln_b      = (const float*)d_in[3];
    const float* innorm_g  = (const float*)d_in[4];
    const float* innorm_b  = (const float*)d_in[5];
    const float* in_proj_w = (const float*)d_in[6];
    const float* in_proj_b = (const float*)d_in[7];
    const float* conv_w    = (const float*)d_in[8];
    const float* conv_b    = (const float*)d_in[9];
    const float* deltaBC_w = (const float*)d_in[10];
    const float* dt_proj_w = (const float*)d_in[11];
    const float* dt_proj_b = (const float*)d_in[12];
    const float* A_log     = (const float*)d_in[13];
    const float* Dp        = (const float*)d_in[14];
    const float* outnorm_g = (const float*)d_in[15];
    const float* outnorm_b = (const float*)d_in[16];
    const float* out_proj_w= (const float*)d_in[17];
    const float* out_proj_b= (const float*)d_in[18];

    float* enc = (float*)d_out;
    char* ws = (char*)d_ws;
    const size_t MB = 1024 * 1024;
    bf16*  h_bf   = (bf16*) (ws + 0);            // 8 MB  [S,d]  (aliased w/ p_bf)
    bf16*  p_bf   = (bf16*) (ws + 0);            // 16 MB [S,di]
    bf16*  xz_bf  = (bf16*) (ws + 16 * MB);      // 32 MB [S,2di]
    float* dlt    = (float*)(ws + 48 * MB);      // 32 MB delta -> y (in place)
    bf16*  u_bf   = (bf16*) (ws + 80 * MB);      // 16 MB [S,di]
    float* dbc    = (float*)(ws + 96 * MB);      // 1.5MB [S,96]
    bf16*  dbc_bf = (bf16*) (ws + 98 * MB);      // 0.5MB [S,64]
    float* dbcp   = (float*)(ws + 99 * MB);      // 6.3MB [4,S,96]
    float* h_end  = (float*)(ws + 106 * MB);     // 16 MB [NC,n,di]
    float* hinit  = (float*)(ws + 122 * MB);     // 16 MB [NC,n,di]
    float* dsum   = (float*)(ws + 138 * MB);     //  1 MB [NC,di]
    bf16*  w_in   = (bf16*) (ws + 139 * MB);     //  8 MB
    bf16*  w_dbc  = (bf16*) (ws + 147 * MB);     // .38MB
    bf16*  w_dt   = (bf16*) (ws + 148 * MB);     // .25MB
    bf16*  w_out  = (bf16*) (ws + 149 * MB);     //  4 MB

    ln_kernel<DMODEL, float><<<SEQ, 256, 0, stream>>>(x, pos, ln_g, ln_b, enc, 1e-6f);

    for (int L = 0; L < NLAYERS; L++) {
        const float* Al = A_log + (size_t)L * DINNER * NSTATE;
        cvt_bf16_kernel<<<(2 * DINNER * DMODEL) / 1024, 256, 0, stream>>>(
            in_proj_w + (size_t)L * 2 * DINNER * DMODEL, w_in);
        cvt_bf16_kernel<<<(96 * DINNER) / 1024, 256, 0, stream>>>(
            deltaBC_w + (size_t)L * 96 * DINNER, w_dbc);
        cvt_bf16_kernel<<<(DINNER * DTRANK) / 1024, 256, 0, stream>>>(
            dt_proj_w + (size_t)L * DINNER * DTRANK, w_dt);
        cvt_bf16_kernel<<<(DMODEL * DINNER) / 1024, 256, 0, stream>>>(
            out_proj_w + (size_t)L * DMODEL * DINNER, w_out);

        ln_kernel<DMODEL, bf16><<<SEQ, 256, 0, stream>>>(enc, nullptr, innorm_g + L * DMODEL,
                                                         innorm_b + L * DMODEL, h_bf, 1e-5f);
        // xz = h @ in_proj_w^T + b  -> bf16   [4096 x 4096], K=1024
        mfma_gemm<0><<<dim3(32, 32), 256, 0, stream>>>(
            h_bf, DMODEL, w_in, DMODEL, in_proj_b + (size_t)L * 2 * DINNER,
            nullptr, 2 * DINNER, nullptr, xz_bf, SEQ, 2 * DINNER, DMODEL);
        conv_kernel<<<(SEQ * 512) / 256, 256, 0, stream>>>(
            xz_bf, conv_w + (size_t)L * DINNER * 3, conv_b + L * DINNER, u_bf);
        // dbc = u @ deltaBC_w^T   split-K x4, K=512 each
        mfma_gemm<1><<<dim3(32, 1, 4), 256, 0, stream>>>(
            u_bf, DINNER, w_dbc, DINNER, nullptr,
            dbcp, 96, nullptr, nullptr, SEQ, 96, 512);
        reduce_dbc_kernel<<<(SEQ * 96) / 256, 256, 0, stream>>>(dbcp, dbc, dbc_bf);
        // delta = softplus(dbc[:,:64] @ dt_proj_w^T + b)   [4096 x 2048], K=64
        mfma_gemm<2><<<dim3(32, 16), 256, 0, stream>>>(
            dbc_bf, DTRANK, w_dt, DTRANK, dt_proj_b + L * DINNER,
            dlt, DINNER, nullptr, nullptr, SEQ, DINNER, DTRANK);
        // selective scan, 3-pass chunked; y overwrites dlt
        scan1_kernel<<<dim3(NC, DINNER / 256), 256, 0, stream>>>(dlt, u_bf, dbc, Al, h_end, dsum);
        scan2_kernel<<<(DINNER * NSTATE) / 256, 256, 0, stream>>>(Al, dsum, h_end, hinit);
        scan3_kernel<<<dim3(NC, DINNER / 256), 256, 0, stream>>>(dlt, u_bf, dbc, Al,
                                                                 Dp + L * DINNER, hinit);
        outnorm_silu_kernel<<<SEQ, 256, 0, stream>>>(dlt, xz_bf, outnorm_g + L * DINNER,
                                                     outnorm_b + L * DINNER, p_bf, 1e-5f);
        // enc = p @ out_proj_w^T + b + enc   [4096 x 1024], K=2048
        mfma_gemm<3><<<dim3(32, 8), 256, 0, stream>>>(
            p_bf, DINNER, w_out, DINNER, out_proj_b + L * DMODEL,
            enc, DMODEL, enc, nullptr, SEQ, DMODEL, DINNER);
    }
}

// Round 4
// 1127.021 us; speedup vs baseline: 7.3198x; 1.0821x over previous
//
#include <hip/hip_runtime.h>
#include <hip/hip_bf16.h>
#include <stdint.h>

// ---------------------------------------------------------------------------
// MambaEncoder forward. Round 4: scan exp-chain fast path (1 exp + 15 muls vs
// 16 exps, runtime-guarded), LC=64 (half state traffic), fused weight cvt.
// ---------------------------------------------------------------------------

#define SEQ     4096
#define DMODEL  1024
#define DINNER  2048
#define NSTATE  16
#define DTRANK  64
#define NLAYERS 4
#define LC      64    // scan chunk length
#define NC      64    // number of chunks (SEQ/LC)

typedef __attribute__((ext_vector_type(8))) short short8v;   // 8 bf16 (4 VGPRs)
typedef __attribute__((ext_vector_type(4))) float f32x4;
typedef __hip_bfloat16 bf16;

__device__ __forceinline__ float b2f(unsigned short x) {
    unsigned int u = ((unsigned int)x) << 16;
    return __builtin_bit_cast(float, u);
}

// ------------------------------------------------------------ async g->LDS 16B
__device__ __forceinline__ void gld16(const void* gsrc, void* ldst) {
    __builtin_amdgcn_global_load_lds(
        (const __attribute__((address_space(1))) void*)gsrc,
        (__attribute__((address_space(3))) void*)ldst, 16, 0, 0);
}

// ---------------------------------------------------------------- block sum
__device__ __forceinline__ float block_sum(float v, float* red, int nwaves) {
    #pragma unroll
    for (int o = 32; o > 0; o >>= 1) v += __shfl_down(v, o, 64);
    int lane = threadIdx.x & 63, w = threadIdx.x >> 6;
    __syncthreads();
    if (lane == 0) red[w] = v;
    __syncthreads();
    float s = red[0];
    for (int i = 1; i < nwaves; i++) s += red[i];
    return s;
}

// ------------------------------------------------------------- layernorm row
template<int WIDTH, typename OutT>
__global__ void ln_kernel(const float* __restrict__ X, const float* __restrict__ X2,
                          const float* __restrict__ g, const float* __restrict__ bta,
                          OutT* __restrict__ out, float eps) {
    constexpr int E = WIDTH / 256;
    __shared__ float red[4];
    int s = blockIdx.x, tid = threadIdx.x;
    size_t base = (size_t)s * WIDTH;
    float v[E]; float sum = 0.f;
    #pragma unroll
    for (int i = 0; i < E; i++) {
        int c = tid + i * 256;
        float t = X[base + c];
        if (X2) t += X2[base + c];
        v[i] = t; sum += t;
    }
    float mu = block_sum(sum, red, 4) * (1.f / WIDTH);
    float sq = 0.f;
    #pragma unroll
    for (int i = 0; i < E; i++) { float d = v[i] - mu; sq += d * d; }
    float var = block_sum(sq, red, 4) * (1.f / WIDTH);
    float rstd = rsqrtf(var + eps);
    #pragma unroll
    for (int i = 0; i < E; i++) {
        int c = tid + i * 256;
        float r = (v[i] - mu) * rstd * g[c] + bta[c];
        out[base + c] = (OutT)r;
    }
}

// --------------------------------------------------- outnorm + silu(z) gate
__global__ void outnorm_silu_kernel(const float* __restrict__ y, const bf16* __restrict__ xz,
                                    const float* __restrict__ g, const float* __restrict__ bta,
                                    bf16* __restrict__ p_bf, float eps) {
    constexpr int WIDTH = DINNER, E = WIDTH / 256;
    __shared__ float red[4];
    int s = blockIdx.x, tid = threadIdx.x;
    size_t base = (size_t)s * WIDTH;
    const unsigned short* xzu = (const unsigned short*)xz;
    float v[E]; float sum = 0.f;
    #pragma unroll
    for (int i = 0; i < E; i++) { int c = tid + i * 256; v[i] = y[base + c]; sum += v[i]; }
    float mu = block_sum(sum, red, 4) * (1.f / WIDTH);
    float sq = 0.f;
    #pragma unroll
    for (int i = 0; i < E; i++) { float d = v[i] - mu; sq += d * d; }
    float var = block_sum(sq, red, 4) * (1.f / WIDTH);
    float rstd = rsqrtf(var + eps);
    #pragma unroll
    for (int i = 0; i < E; i++) {
        int c = tid + i * 256;
        float ln = (v[i] - mu) * rstd * g[c] + bta[c];
        float z = b2f(xzu[(size_t)s * (2 * DINNER) + DINNER + c]);
        float sig = 1.f / (1.f + __expf(-z));
        p_bf[base + c] = __float2bfloat16(ln * (z * sig));
    }
}

// ------------------------------------------------------- depthwise conv, k=3
__global__ void conv_kernel(const bf16* __restrict__ xz, const float* __restrict__ cw,
                            const float* __restrict__ cb, bf16* __restrict__ u_bf) {
    int t = blockIdx.x * 256 + threadIdx.x;     // SEQ * 512
    int s = t >> 9, c = (t & 511) * 4;
    size_t row = (size_t)s * (2 * DINNER);
    const unsigned short* xp = (const unsigned short*)xz;
    ushort4 z4 = {0, 0, 0, 0};
    ushort4 v0 = *(const ushort4*)(xp + row + c);
    ushort4 vm = (s > 0)       ? *(const ushort4*)(xp + row - 2 * DINNER + c) : z4;
    ushort4 vp = (s < SEQ - 1) ? *(const ushort4*)(xp + row + 2 * DINNER + c) : z4;
    unsigned short o[4];
    float x0[4] = {b2f(v0.x), b2f(v0.y), b2f(v0.z), b2f(v0.w)};
    float xm[4] = {b2f(vm.x), b2f(vm.y), b2f(vm.z), b2f(vm.w)};
    float xp4[4] = {b2f(vp.x), b2f(vp.y), b2f(vp.z), b2f(vp.w)};
    #pragma unroll
    for (int i = 0; i < 4; i++) {
        int ch = c + i;
        float u = cw[ch * 3 + 0] * xm[i] + cw[ch * 3 + 1] * x0[i]
                + cw[ch * 3 + 2] * xp4[i] + cb[ch];
        o[i] = __builtin_bit_cast(unsigned short, __float2bfloat16(u));
    }
    *(ushort4*)((unsigned short*)u_bf + (size_t)s * DINNER + c) = {o[0], o[1], o[2], o[3]};
}

// ------------------------------- fused fp32 -> bf16 cvt for 4 weight tensors
#define CN0 (2 * DINNER * DMODEL)   // 4194304 in_proj
#define CN1 (DMODEL * DINNER)       // 2097152 out_proj
#define CN2 (96 * DINNER)           //  196608 deltaBC
#define CN3 (DINNER * DTRANK)       //  131072 dt_proj
__global__ void cvt_all_kernel(const float* __restrict__ w0, const float* __restrict__ w1,
                               const float* __restrict__ w2, const float* __restrict__ w3,
                               bf16* __restrict__ o0, bf16* __restrict__ o1,
                               bf16* __restrict__ o2, bf16* __restrict__ o3) {
    size_t i = (size_t)(blockIdx.x * 256 + threadIdx.x) * 4;
    const float* src; bf16* dst;
    if (i < CN0)                   { src = w0; dst = o0; }
    else if (i < CN0 + CN1)        { src = w1; dst = o1; i -= CN0; }
    else if (i < CN0 + CN1 + CN2)  { src = w2; dst = o2; i -= CN0 + CN1; }
    else                           { src = w3; dst = o3; i -= CN0 + CN1 + CN2; }
    float4 v = *(const float4*)(src + i);
    __hip_bfloat162 t0, t1;
    t0.x = __float2bfloat16(v.x); t0.y = __float2bfloat16(v.y);
    t1.x = __float2bfloat16(v.z); t1.y = __float2bfloat16(v.w);
    __hip_bfloat162* o = (__hip_bfloat162*)(dst + i);
    o[0] = t0; o[1] = t1;
}

// --------------------------------------------------------- bf16 MFMA GEMM
// MODE 0: +bias, bf16 out (in_proj)   MODE 1: split-K partial, N=96 (dbc)
// MODE 2: +bias, softplus, f32 out    MODE 3: +bias, +res, f32 out (out_proj)
template<int MODE>
__global__ __launch_bounds__(256, 2)
void mfma_gemm(const bf16* __restrict__ A, int lda,
               const bf16* __restrict__ W, int ldw,
               const float* __restrict__ bias,
               float* __restrict__ C, int ldc,
               const float* __restrict__ res,
               bf16* __restrict__ Cbf,
               int M, int N, int K) {
    __shared__ __attribute__((aligned(16))) short sA[128][32];
    __shared__ __attribute__((aligned(16))) short sB[128][32];
    int tid = threadIdx.x;
    int lane = tid & 63, w = tid >> 6;
    int wm = w >> 1, wn = w & 1;
    int m0 = blockIdx.x * 128, n0 = blockIdx.y * 128;
    int r16 = lane & 15, quad = lane >> 4;
    int ldrow = (lane >> 2);
    int c8 = (lane & 3) * 8;

    if (MODE == 1) {       // split-K over blockIdx.z
        int kz = blockIdx.z;
        A += (size_t)kz * K;
        W += (size_t)kz * K;
        C += (size_t)kz * M * 96;
    }

    f32x4 acc[4][4] = {};

    for (int k0 = 0; k0 < K; k0 += 32) {
        __syncthreads();
        #pragma unroll
        for (int j = 0; j < 2; j++) {
            int row = j * 64 + w * 16 + ldrow;
            gld16(A + (size_t)(m0 + row) * lda + k0 + c8,
                  (char*)&sA[0][0] + j * 4096 + w * 1024);
            int nr = n0 + row; if (nr > N - 1) nr = N - 1;   // clamp (MODE 1)
            gld16(W + (size_t)nr * ldw + k0 + c8,
                  (char*)&sB[0][0] + j * 4096 + w * 1024);
        }
        __syncthreads();
        short8v aF[4], bF[4];
        #pragma unroll
        for (int mi = 0; mi < 4; mi++)
            aF[mi] = *(const short8v*)&sA[wm * 64 + mi * 16 + r16][quad * 8];
        #pragma unroll
        for (int ni = 0; ni < 4; ni++)
            bF[ni] = *(const short8v*)&sB[wn * 64 + ni * 16 + r16][quad * 8];
        #pragma unroll
        for (int mi = 0; mi < 4; mi++)
            #pragma unroll
            for (int ni = 0; ni < 4; ni++)
                acc[mi][ni] = __builtin_amdgcn_mfma_f32_16x16x32_bf16(
                    aF[mi], bF[ni], acc[mi][ni], 0, 0, 0);
    }

    #pragma unroll
    for (int mi = 0; mi < 4; mi++) {
        #pragma unroll
        for (int ni = 0; ni < 4; ni++) {
            f32x4 a = acc[mi][ni];
            int col = n0 + wn * 64 + ni * 16 + r16;
            int rbase = m0 + wm * 64 + mi * 16 + quad * 4;
            #pragma unroll
            for (int r = 0; r < 4; r++) {
                int row = rbase + r;
                float v = a[r];
                if (MODE == 0 || MODE == 2 || MODE == 3) v += bias[col];
                if (MODE == 2) v = (v > 20.f) ? v : log1pf(__expf(v));
                if (MODE == 3) v += res[(size_t)row * ldc + col];
                if (MODE == 1) {
                    if (col < 96) C[(size_t)row * 96 + col] = v;
                } else if (MODE == 0) {
                    Cbf[(size_t)row * ldc + col] = __float2bfloat16(v);
                } else {
                    C[(size_t)row * ldc + col] = v;
                }
            }
        }
    }
}

// -------------------------------------------- reduce split-K partials of dbc
__global__ void reduce_dbc_kernel(const float* __restrict__ p, float* __restrict__ dbc,
                                  bf16* __restrict__ dbc_bf) {
    int i = blockIdx.x * 256 + threadIdx.x;      // SEQ*96
    const int SP = SEQ * 96;
    float v = p[i] + p[i + SP] + p[i + 2 * SP] + p[i + 3 * SP];
    dbc[i] = v;
    int row = i / 96, c = i - row * 96;
    if (c < DTRANK) dbc_bf[(size_t)row * DTRANK + c] = __float2bfloat16(v);
}

// --------------------------------------------------- exp-chain detection
__device__ __forceinline__ bool a_is_neg_integers(const float* a) {
    bool fast = true;
    #pragma unroll
    for (int n = 0; n < NSTATE; n++)
        fast = fast && (__builtin_fabsf(a[n] + (float)(n + 1)) < 1e-3f * (n + 1));
    return fast;
}

// ------------------------------------------------------- chunked scan pass 1
__global__ void scan1_kernel(const float* __restrict__ delta, const bf16* __restrict__ u,
                             const float* __restrict__ dbc, const float* __restrict__ A_log,
                             float* __restrict__ h_end, float* __restrict__ dsum) {
    __shared__ __attribute__((aligned(16))) float sB[LC][NSTATE];
    int k = blockIdx.x, d = blockIdx.y * 256 + threadIdx.x;
    int s0 = k * LC, tid = threadIdx.x;
    #pragma unroll
    for (int i = 0; i < 4; i++) {
        int idx = tid + i * 256;                 // LC*16 = 1024
        int r = idx >> 4, n = idx & 15;
        sB[r][n] = dbc[(size_t)(s0 + r) * 96 + DTRANK + n];
    }
    float a[NSTATE];
    #pragma unroll
    for (int n = 0; n < NSTATE; n++) a[n] = -__expf(A_log[(size_t)d * NSTATE + n]);
    bool fast = a_is_neg_integers(a);
    __syncthreads();
    const unsigned short* uu16 = (const unsigned short*)u;
    float h[NSTATE] = {}; float ds = 0.f;
    if (fast) {
        #pragma unroll 2
        for (int r = 0; r < LC; r++) {
            float dl = delta[(size_t)(s0 + r) * DINNER + d];
            float du = dl * b2f(uu16[(size_t)(s0 + r) * DINNER + d]);
            ds += dl;
            float g = __expf(-dl);
            float Bv[NSTATE];
            #pragma unroll
            for (int q = 0; q < 4; q++) *(float4*)&Bv[q * 4] = *(const float4*)&sB[r][q * 4];
            float fac = 1.f;
            #pragma unroll
            for (int n = 0; n < NSTATE; n++) {
                fac *= g;
                h[n] = fac * h[n] + du * Bv[n];
            }
        }
    } else {
        #pragma unroll 2
        for (int r = 0; r < LC; r++) {
            float dl = delta[(size_t)(s0 + r) * DINNER + d];
            float du = dl * b2f(uu16[(size_t)(s0 + r) * DINNER + d]);
            ds += dl;
            float Bv[NSTATE];
            #pragma unroll
            for (int q = 0; q < 4; q++) *(float4*)&Bv[q * 4] = *(const float4*)&sB[r][q * 4];
            #pragma unroll
            for (int n = 0; n < NSTATE; n++)
                h[n] = __expf(dl * a[n]) * h[n] + du * Bv[n];
        }
    }
    #pragma unroll
    for (int n = 0; n < NSTATE; n++)
        h_end[((size_t)k * NSTATE + n) * DINNER + d] = h[n];
    dsum[(size_t)k * DINNER + d] = ds;
}

// ------------------------------------------------------- chunked scan pass 2
__global__ void scan2_kernel(const float* __restrict__ A_log, const float* __restrict__ dsum,
                             const float* __restrict__ h_end, float* __restrict__ hinit) {
    int id = blockIdx.x * 256 + threadIdx.x;     // DINNER*NSTATE
    int d = id & (DINNER - 1), n = id >> 11;
    float a = -__expf(A_log[(size_t)d * NSTATE + n]);
    float h = 0.f;
    for (int k = 0; k < NC; k++) {
        size_t off = ((size_t)k * NSTATE + n) * DINNER + d;
        hinit[off] = h;
        h = __expf(a * dsum[(size_t)k * DINNER + d]) * h + h_end[off];
    }
}

// ------------------------------------------------------- chunked scan pass 3
__global__ void scan3_kernel(float* __restrict__ delta_y, const bf16* __restrict__ u,
                             const float* __restrict__ dbc, const float* __restrict__ A_log,
                             const float* __restrict__ Dp, const float* __restrict__ hinit) {
    __shared__ __attribute__((aligned(16))) float sB[LC][NSTATE];
    __shared__ __attribute__((aligned(16))) float sC[LC][NSTATE];
    int k = blockIdx.x, d = blockIdx.y * 256 + threadIdx.x;
    int s0 = k * LC, tid = threadIdx.x;
    #pragma unroll
    for (int i = 0; i < 8; i++) {
        int idx = tid + i * 256;                 // LC*32 = 2048
        int r = idx >> 5, c = idx & 31;
        float v = dbc[(size_t)(s0 + r) * 96 + DTRANK + c];
        if (c < 16) sB[r][c] = v; else sC[r][c - 16] = v;
    }
    float a[NSTATE];
    #pragma unroll
    for (int n = 0; n < NSTATE; n++) a[n] = -__expf(A_log[(size_t)d * NSTATE + n]);
    bool fast = a_is_neg_integers(a);
    float h[NSTATE];
    #pragma unroll
    for (int n = 0; n < NSTATE; n++)
        h[n] = hinit[((size_t)k * NSTATE + n) * DINNER + d];
    float dpv = Dp[d];
    __syncthreads();
    const unsigned short* uu16 = (const unsigned short*)u;
    if (fast) {
        #pragma unroll 2
        for (int r = 0; r < LC; r++) {
            float dl = delta_y[(size_t)(s0 + r) * DINNER + d];
            float uu = b2f(uu16[(size_t)(s0 + r) * DINNER + d]);
            float du = dl * uu;
            float g = __expf(-dl);
            float Bv[NSTATE], Cv[NSTATE];
            #pragma unroll
            for (int q = 0; q < 4; q++) {
                *(float4*)&Bv[q * 4] = *(const float4*)&sB[r][q * 4];
                *(float4*)&Cv[q * 4] = *(const float4*)&sC[r][q * 4];
            }
            float y = uu * dpv;
            float fac = 1.f;
            #pragma unroll
            for (int n = 0; n < NSTATE; n++) {
                fac *= g;
                h[n] = fac * h[n] + du * Bv[n];
                y += h[n] * Cv[n];
            }
            delta_y[(size_t)(s0 + r) * DINNER + d] = y;
        }
    } else {
        #pragma unroll 2
        for (int r = 0; r < LC; r++) {
            float dl = delta_y[(size_t)(s0 + r) * DINNER + d];
            float uu = b2f(uu16[(size_t)(s0 + r) * DINNER + d]);
            float du = dl * uu;
            float Bv[NSTATE], Cv[NSTATE];
            #pragma unroll
            for (int q = 0; q < 4; q++) {
                *(float4*)&Bv[q * 4] = *(const float4*)&sB[r][q * 4];
                *(float4*)&Cv[q * 4] = *(const float4*)&sC[r][q * 4];
            }
            float y = uu * dpv;
            #pragma unroll
            for (int n = 0; n < NSTATE; n++) {
                h[n] = __expf(dl * a[n]) * h[n] + du * Bv[n];
                y += h[n] * Cv[n];
            }
            delta_y[(size_t)(s0 + r) * DINNER + d] = y;
        }
    }
}

// ---------------------------------------------------------------------------
extern "C" void kernel_launch(void* const* d_in, const int* in_sizes, int n_in,
                              void* d_out, int out_size, void* d_ws, size_t ws_size,
                              hipStream_t stream) {
    const float* x         = (const float*)d_in[0];
    const float* pos       = (const float*)d_in[1];
    const float* ln_g      = (const float*)d_in[2];
    const float* ln_b      = (const float*)d_in[3];
    const float* innorm_g  = (const float*)d_in[4];
    const float* innorm_b  = (const float*)d_in[5];
    const float* in_proj_w = (const float*)d_in[6];
    const float* in_proj_b = (const float*)d_in[7];
    const float* conv_w    = (const float*)d_in[8];
    const float* conv_b    = (const float*)d_in[9];
    const float* deltaBC_w = (const float*)d_in[10];
    const float* dt_proj_w = (const float*)d_in[11];
    const float* dt_proj_b = (const float*)d_in[12];
    const float* A_log     = (const float*)d_in[13];
    const float* Dp        = (const float*)d_in[14];
    const float* outnorm_g = (const float*)d_in[15];
    const float* outnorm_b = (const float*)d_in[16];
    const float* out_proj_w= (const float*)d_in[17];
    const float* out_proj_b= (const float*)d_in[18];

    float* enc = (float*)d_out;
    char* ws = (char*)d_ws;
    const size_t MB = 1024 * 1024;
    bf16*  h_bf   = (bf16*) (ws + 0);            //  8 MB [S,d]  (aliased w/ p_bf)
    bf16*  p_bf   = (bf16*) (ws + 0);            // 16 MB [S,di]
    bf16*  xz_bf  = (bf16*) (ws + 16 * MB);      // 32 MB [S,2di]
    float* dlt    = (float*)(ws + 48 * MB);      // 32 MB delta -> y (in place)
    float* dbcp   = (float*)(ws + 48 * MB);      //  6 MB splitK partials (alias dlt)
    bf16*  u_bf   = (bf16*) (ws + 80 * MB);      // 16 MB [S,di]
    float* dbc    = (float*)(ws + 96 * MB);      // 1.5MB [S,96]
    bf16*  dbc_bf = (bf16*) (ws + 98 * MB);      // 0.5MB [S,64]
    float* h_end  = (float*)(ws + 99 * MB);      //  8 MB [NC,n,di]
    float* hinit  = (float*)(ws + 107 * MB);     //  8 MB [NC,n,di]
    float* dsum   = (float*)(ws + 115 * MB);     // 0.5MB [NC,di]
    bf16*  w_in   = (bf16*) (ws + 116 * MB);     //  8 MB
    bf16*  w_dbc  = (bf16*) (ws + 124 * MB);     // .38MB
    bf16*  w_dt   = (bf16*) (ws + 125 * MB);     // .25MB
    bf16*  w_out  = (bf16*) (ws + 126 * MB);     //  4 MB  -> total 130 MB

    ln_kernel<DMODEL, float><<<SEQ, 256, 0, stream>>>(x, pos, ln_g, ln_b, enc, 1e-6f);

    for (int L = 0; L < NLAYERS; L++) {
        const float* Al = A_log + (size_t)L * DINNER * NSTATE;
        // fused weight conversion: all 4 tensors of this layer in one launch
        cvt_all_kernel<<<(CN0 + CN1 + CN2 + CN3) / 1024, 256, 0, stream>>>(
            in_proj_w + (size_t)L * CN0, out_proj_w + (size_t)L * CN1,
            deltaBC_w + (size_t)L * CN2, dt_proj_w + (size_t)L * CN3,
            w_in, w_out, w_dbc, w_dt);

        ln_kernel<DMODEL, bf16><<<SEQ, 256, 0, stream>>>(enc, nullptr, innorm_g + L * DMODEL,
                                                         innorm_b + L * DMODEL, h_bf, 1e-5f);
        // xz = h @ in_proj_w^T + b  -> bf16   [4096 x 4096], K=1024
        mfma_gemm<0><<<dim3(32, 32), 256, 0, stream>>>(
            h_bf, DMODEL, w_in, DMODEL, in_proj_b + (size_t)L * 2 * DINNER,
            nullptr, 2 * DINNER, nullptr, xz_bf, SEQ, 2 * DINNER, DMODEL);
        conv_kernel<<<(SEQ * 512) / 256, 256, 0, stream>>>(
            xz_bf, conv_w + (size_t)L * DINNER * 3, conv_b + L * DINNER, u_bf);
        // dbc = u @ deltaBC_w^T   split-K x4, K=512 each
        mfma_gemm<1><<<dim3(32, 1, 4), 256, 0, stream>>>(
            u_bf, DINNER, w_dbc, DINNER, nullptr,
            dbcp, 96, nullptr, nullptr, SEQ, 96, 512);
        reduce_dbc_kernel<<<(SEQ * 96) / 256, 256, 0, stream>>>(dbcp, dbc, dbc_bf);
        // delta = softplus(dbc[:,:64] @ dt_proj_w^T + b)   [4096 x 2048], K=64
        mfma_gemm<2><<<dim3(32, 16), 256, 0, stream>>>(
            dbc_bf, DTRANK, w_dt, DTRANK, dt_proj_b + L * DINNER,
            dlt, DINNER, nullptr, nullptr, SEQ, DINNER, DTRANK);
        // selective scan, 3-pass chunked; y overwrites dlt
        scan1_kernel<<<dim3(NC, DINNER / 256), 256, 0, stream>>>(dlt, u_bf, dbc, Al, h_end, dsum);
        scan2_kernel<<<(DINNER * NSTATE) / 256, 256, 0, stream>>>(Al, dsum, h_end, hinit);
        scan3_kernel<<<dim3(NC, DINNER / 256), 256, 0, stream>>>(dlt, u_bf, dbc, Al,
                                                                 Dp + L * DINNER, hinit);
        outnorm_silu_kernel<<<SEQ, 256, 0, stream>>>(dlt, xz_bf, outnorm_g + L * DINNER,
                                                     outnorm_b + L * DINNER, p_bf, 1e-5f);
        // enc = p @ out_proj_w^T + b + enc   [4096 x 1024], K=2048
        mfma_gemm<3><<<dim3(32, 8), 256, 0, stream>>>(
            p_bf, DINNER, w_out, DINNER, out_proj_b + L * DMODEL,
            enc, DMODEL, enc, nullptr, SEQ, DMODEL, DINNER);
    }
}